// Round 9
// baseline (4081.866 us; speedup 1.0000x reference)
//
#include <hip/hip_runtime.h>
#include <hip/hip_bf16.h>
#include <stdint.h>

// Persistent LSTM v3: 16 groups (16 batches) x 16 WGs (32 hids) x 4 waves.
// Weights register-resident. h published via 8B global_atomic_exchange
// (performed AT the LLC -> no HBM write-through on the release path),
// per-wave step slots + parallel 64-lane ballot poll (no serialized RMW).

#define NB 256
#define NT 512
#define NF 130
#define NK 128
#define NH 512

typedef float f32x4 __attribute__((ext_vector_type(4)));
typedef float f32x2 __attribute__((ext_vector_type(2)));
typedef short bf16x8 __attribute__((ext_vector_type(8)));

__device__ __forceinline__ unsigned bf1(float f) {
  union { float f; uint32_t u; } v; v.f = f;
  return (v.u + 0x7FFFu + ((v.u >> 16) & 1u)) >> 16;  // RNE, low 16 bits valid
}

__device__ __forceinline__ bf16x8 cvt8(const float* p) {
  bf16x8 r;
#pragma unroll
  for (int i = 0; i < 4; ++i) {
    f32x2 t = *(const f32x2*)(p + 2 * i);
    r[2 * i]     = (short)bf1(t[0]);
    r[2 * i + 1] = (short)bf1(t[1]);
  }
  return r;
}

__device__ __forceinline__ float fsig(float x) {
  return __builtin_amdgcn_rcpf(1.0f + __builtin_amdgcn_exp2f(-1.44269504f * x));
}
__device__ __forceinline__ float ftanh(float x) {
  return 2.0f * __builtin_amdgcn_rcpf(1.0f + __builtin_amdgcn_exp2f(-2.88539008f * x)) - 1.0f;
}

__global__ __launch_bounds__(256, 1) void lstm_pers(
    const float* __restrict__ xin, const int* __restrict__ lens,
    const float* __restrict__ h0, const float* __restrict__ c0,
    const float* __restrict__ Wih, const float* __restrict__ Whh,
    const float* __restrict__ bih, const float* __restrict__ bhh,
    float* __restrict__ out, unsigned* __restrict__ slots,
    unsigned short* __restrict__ hbuf /* [2][NB][NH] bf16 bits */) {
  const int blk = blockIdx.x;
  const int g  = blk & 15;   // batch group (blk%8 const within group -> XCD-affine)
  const int s  = blk >> 4;   // hidden slice 0..15
  const int tid = threadIdx.x;
  const int w  = tid >> 6;
  const int l  = tid & 63;
  const int q  = l >> 4;
  const int col = l & 15;
  const int bidx = (g << 4) + col;
  const int qh = (l & 15) >> 2;
  const int sg = l & 3;
  const int hbase = (s << 5) + (w << 3); // wave's 8 hids
  const int wid = (s << 2) + w;          // wave id within group, 0..63
  unsigned* slot = slots + g * 64;

  // ---- weights -> registers (once) ----
  bf16x8 whh[2][16];
  bf16x8 wih[2][4];
#pragma unroll
  for (int m = 0; m < 2; ++m) {
    const int grow = sg * NH + hbase + (m << 2) + qh;
    const float* pw = Whh + (size_t)grow * NH + q * 8;
#pragma unroll
    for (int kt = 0; kt < 16; ++kt) whh[m][kt] = cvt8(pw + kt * 32);
    const float* pi = Wih + (size_t)grow * NK + q * 8;
#pragma unroll
    for (int kt = 0; kt < 4; ++kt) wih[m][kt] = cvt8(pi + kt * 32);
  }

  f32x4 bias[2];
  float cst[2];
  const int blen = lens[bidx];
#pragma unroll
  for (int m = 0; m < 2; ++m) {
    const int hid = hbase + (m << 2) + q;
#pragma unroll
    for (int p = 0; p < 4; ++p)
      bias[m][p] = bih[p * NH + hid] + bhh[p * NH + hid];
    cst[m] = c0[(size_t)bidx * NH + hid];
  }

  // pack helper: val32 = bf16(m=0) | bf16(m=1)<<16 per lane; gather the 4
  // q-slices of each column via bpermute; lanes<32 swap 8B (4 hids) at LLC.
#define PUBLISH(val32, hw)                                                        \
  {                                                                               \
    unsigned pv0 = __builtin_amdgcn_ds_bpermute((col + 0) * 4, (int)(val32));     \
    unsigned pv1 = __builtin_amdgcn_ds_bpermute((col + 16) * 4, (int)(val32));    \
    unsigned pv2 = __builtin_amdgcn_ds_bpermute((col + 32) * 4, (int)(val32));    \
    unsigned pv3 = __builtin_amdgcn_ds_bpermute((col + 48) * 4, (int)(val32));    \
    if (l < 32) {                                                                 \
      unsigned lo, hi;                                                            \
      if (q == 0) { lo = (pv0 & 0xFFFFu) | (pv1 << 16);                           \
                    hi = (pv2 & 0xFFFFu) | (pv3 << 16); }                         \
      else        { lo = (pv0 >> 16) | (pv1 & 0xFFFF0000u);                       \
                    hi = (pv2 >> 16) | (pv3 & 0xFFFF0000u); }                     \
      unsigned long long pk = ((unsigned long long)hi << 32) | lo;                \
      unsigned long long* dst =                                                   \
          (unsigned long long*)((hw) + hbase + (q ? 4 : 0));                      \
      (void)__hip_atomic_exchange(dst, pk, __ATOMIC_RELAXED,                      \
                                  __HIP_MEMORY_SCOPE_AGENT);                      \
    }                                                                             \
  }

  // ---- publish h0 (buffer 0) ----
  {
    unsigned b0 = bf1(h0[(size_t)bidx * NH + hbase + 0 + q]);
    unsigned b1 = bf1(h0[(size_t)bidx * NH + hbase + 4 + q]);
    unsigned val32 = b0 | (b1 << 16);
    unsigned short* hw = hbuf + (size_t)bidx * NH;
    PUBLISH(val32, hw);
  }
  asm volatile("s_waitcnt vmcnt(0)" ::: "memory");  // swaps done at LLC
  if (l == 0)
    (void)__hip_atomic_exchange(slot + wid, 1u, __ATOMIC_RELAXED,
                                __HIP_MEMORY_SCOPE_AGENT);

  // x(0) prefetch
  const float* px0 = xin + (size_t)bidx * (NT * NF) + q * 8;
  f32x2 xr[16];
#pragma unroll
  for (int kt = 0; kt < 4; ++kt)
#pragma unroll
    for (int i = 0; i < 4; ++i)
      xr[kt * 4 + i] = *(const f32x2*)(px0 + kt * 32 + i * 2);

  const unsigned short* hsb = hbuf + (size_t)bidx * NH + q * 8;
  unsigned short* hwb = hbuf + (size_t)bidx * NH;
  int dead = 0;

  for (int t = 0; t < NT; ++t) {
    // consume xr -> bf16, then immediately issue x(t+1) prefetch (overlaps all)
    bf16x8 xf[4];
#pragma unroll
    for (int kt = 0; kt < 4; ++kt)
#pragma unroll
      for (int i = 0; i < 4; ++i) {
        xf[kt][2 * i]     = (short)bf1(xr[kt * 4 + i][0]);
        xf[kt][2 * i + 1] = (short)bf1(xr[kt * 4 + i][1]);
      }
    {
      const int tp = (t + 1 < NT) ? t + 1 : NT - 1;
      const float* px = px0 + (size_t)tp * NF;
#pragma unroll
      for (int kt = 0; kt < 4; ++kt)
#pragma unroll
        for (int i = 0; i < 4; ++i)
          xr[kt * 4 + i] = *(const f32x2*)(px + kt * 32 + i * 2);
    }
    // x-projection
    f32x4 accA[2], accB[2];
    accA[0] = bias[0]; accA[1] = bias[1];
    accB[0] = (f32x4){0.f, 0.f, 0.f, 0.f}; accB[1] = accB[0];
#pragma unroll
    for (int kt = 0; kt < 4; ++kt)
#pragma unroll
      for (int m = 0; m < 2; ++m)
        accA[m] = __builtin_amdgcn_mfma_f32_16x16x32_bf16(wih[m][kt], xf[kt], accA[m], 0, 0, 0);
    // ---- parallel poll: lane i watches wave i's slot ----
    if (!dead) {
      const unsigned tgt = (unsigned)(t + 1);
      int iters = 0;
      for (;;) {
        unsigned sv = __hip_atomic_load(slot + l, __ATOMIC_RELAXED,
                                        __HIP_MEMORY_SCOPE_AGENT);
        if (__ballot(sv < tgt) == 0ULL) break;
        __builtin_amdgcn_s_sleep(1);
        if (++iters > (1 << 17)) { dead = 1; break; }
      }
    }
    asm volatile("" ::: "memory");  // keep h loads below the poll
    // ---- h loads (8B agent-scope, all issued up front) ----
    const unsigned short* hs = hsb + ((size_t)(t & 1)) * (NB * NH);
    union U { unsigned long long u[2]; bf16x8 v; };
    U hu[16];
#pragma unroll
    for (int kt = 0; kt < 16; ++kt) {
      hu[kt].u[0] = __hip_atomic_load((const unsigned long long*)(hs + kt * 32),
                                      __ATOMIC_RELAXED, __HIP_MEMORY_SCOPE_AGENT);
      hu[kt].u[1] = __hip_atomic_load((const unsigned long long*)(hs + kt * 32 + 4),
                                      __ATOMIC_RELAXED, __HIP_MEMORY_SCOPE_AGENT);
    }
#pragma unroll
    for (int kt = 0; kt < 16; ++kt) {
#pragma unroll
      for (int m = 0; m < 2; ++m) {
        if (kt & 1)
          accB[m] = __builtin_amdgcn_mfma_f32_16x16x32_bf16(whh[m][kt], hu[kt].v, accB[m], 0, 0, 0);
        else
          accA[m] = __builtin_amdgcn_mfma_f32_16x16x32_bf16(whh[m][kt], hu[kt].v, accA[m], 0, 0, 0);
      }
    }
    // ---- nonlinearity + publish ----
    unsigned short* hw = hwb + ((size_t)((t + 1) & 1)) * (NB * NH);
    unsigned hbits[2];
#pragma unroll
    for (int m = 0; m < 2; ++m) {
      f32x4 gv = accA[m] + accB[m];
      float ig = fsig(gv[0]);
      float fg = fsig(gv[1]);
      float gg = ftanh(gv[2]);
      float og = fsig(gv[3]);
      float cc = fg * cst[m] + ig * gg;
      cst[m] = cc;
      float hh = og * ftanh(cc);
      hbits[m] = bf1(hh);
      if (t == blen - 1) out[(size_t)bidx * NH + hbase + (m << 2) + q] = hh;
    }
    {
      unsigned val32 = hbits[0] | (hbits[1] << 16);
      PUBLISH(val32, hw);
    }
    asm volatile("s_waitcnt vmcnt(0)" ::: "memory");  // swaps complete at LLC
    if (l == 0)
      (void)__hip_atomic_exchange(slot + wid, (unsigned)(t + 2),
                                  __ATOMIC_RELAXED, __HIP_MEMORY_SCOPE_AGENT);
  }
}

extern "C" void kernel_launch(void* const* d_in, const int* in_sizes, int n_in,
                              void* d_out, int out_size, void* d_ws, size_t ws_size,
                              hipStream_t stream) {
  const float* xin  = (const float*)d_in[0];
  const int*   lens = (const int*)d_in[1];
  const float* h0   = (const float*)d_in[2];
  const float* c0   = (const float*)d_in[3];
  const float* Wih  = (const float*)d_in[4];
  const float* Whh  = (const float*)d_in[5];
  const float* bih  = (const float*)d_in[6];
  const float* bhh  = (const float*)d_in[7];
  float* out = (float*)d_out;

  unsigned* slots = (unsigned*)d_ws;                            // 16 groups x 64 x 4B = 4KB
  unsigned short* hbuf = (unsigned short*)((char*)d_ws + 4096); // 2*256*512 bf16

  hipMemsetAsync(d_ws, 0, 4096, stream);  // zero slots
  lstm_pers<<<dim3(256), dim3(256), 0, stream>>>(xin, lens, h0, c0, Wih, Whh, bih, bhh,
                                                 out, slots, hbuf);
}